// Round 2
// baseline (552.402 us; speedup 1.0000x reference)
//
#include <hip/hip_runtime.h>
#include <hip/hip_fp16.h>
#include <math.h>

// Fused separable 11x11 gaussian over {x,y,x2,y2,xy} + SSIM/charb/MSE combine.
// R1: fp16-packed LDS (28.5 KB -> 5 blocks/CU vs 54.8 KB -> 2), interior-block
// fast path with float4 loads, rcp-based epilogue.
//
// LDS strides chosen so (row*68 + 8*cg) is provably 0 mod 4 -> ds_write_b128
// merges in phase A; phase-B reads are lane-consecutive (2-way bank aliasing
// only => free).

#define TW 64
#define TH 32
#define RAD 5
#define KW 11
#define RAW_H (TH + 2 * RAD)   // 42
#define SA 68                  // half2-array stride (dword entries)
#define SC 68                  // half-array stride
#define IMG 512

#define C1F 1e-4f
#define C2F 9e-4f
#define EPS2 1e-12f

__global__ __launch_bounds__(256, 5)
void CombinedLossSSIMCharbMSE_81372450390186_kernel(
    const float* __restrict__ pred,
    const float* __restrict__ target,
    float* __restrict__ out)
{
    __shared__ __half2 shA[RAW_H * SA];  // (hx, hy)
    __shared__ __half2 shB[RAW_H * SA];  // (hxx, hyy)
    __shared__ __half  shC[RAW_H * SC];  // hxy

    const int tid = threadIdx.x;
    const int bx = blockIdx.x, by = blockIdx.y;
    const int tx0 = bx * TW, ty0 = by * TH;
    const size_t plane = (size_t)blockIdx.z * (IMG * IMG);
    const float* __restrict__ pp = pred + plane;
    const float* __restrict__ tp = target + plane;
    float* __restrict__ op = out + plane;

    // Gaussian weights (sigma=1.5), normalized; registers (compile-time idx).
    float W[KW];
    {
        float s = 0.f;
#pragma unroll
        for (int i = 0; i < KW; ++i) {
            float x = (float)(i - RAD);
            W[i] = __expf(-x * x * (1.0f / (2.0f * 1.5f * 1.5f)));
            s += W[i];
        }
        float inv = 1.0f / s;
#pragma unroll
        for (int i = 0; i < KW; ++i) W[i] *= inv;
    }

    const bool xint = (bx > 0) & (bx < (IMG / TW - 1));

    // ---- Phase A: horizontal filter (fused with global read) ----
    // item = r*8 + cg; r in [0,42), cg = 8-column group.
    for (int item = tid; item < RAW_H * 8; item += 256) {
        const int r = item >> 3;
        const int c0 = (item & 7) * 8;
        const int gy = ty0 - RAD + r;

        float ax[8] = {0, 0, 0, 0, 0, 0, 0, 0};
        float ay[8] = {0, 0, 0, 0, 0, 0, 0, 0};
        float axx[8] = {0, 0, 0, 0, 0, 0, 0, 0};
        float ayy[8] = {0, 0, 0, 0, 0, 0, 0, 0};
        float axy[8] = {0, 0, 0, 0, 0, 0, 0, 0};

        if (gy >= 0 && gy < IMG) {
            const float* __restrict__ prow = pp + gy * IMG;
            const float* __restrict__ trow = tp + gy * IMG;
            if (xint) {
                // Window [tx0+c0-8, tx0+c0+16): 6 aligned float4 loads.
                // Output col c0+j tap k -> rel idx = j + k + 3 in [3,20].
                const int gx0 = tx0 + c0 - 8;
                const float4* __restrict__ p4 = (const float4*)(prow + gx0);
                const float4* __restrict__ t4 = (const float4*)(trow + gx0);
#pragma unroll
                for (int ch = 0; ch < 6; ++ch) {
                    const float4 xv = p4[ch];
                    const float4 yv = t4[ch];
                    const float xs[4] = {xv.x, xv.y, xv.z, xv.w};
                    const float ys[4] = {yv.x, yv.y, yv.z, yv.w};
#pragma unroll
                    for (int q = 0; q < 4; ++q) {
                        const int idx = ch * 4 + q;
                        if (idx >= 3 && idx <= 20) {
                            const float px = xs[q], py = ys[q];
                            const float pxx = px * px, pyy = py * py, pxy = px * py;
#pragma unroll
                            for (int j = 0; j < 8; ++j) {
                                const int m = idx - 3 - j;   // tap index
                                if (m >= 0 && m < KW) {
                                    const float w = W[m];
                                    ax[j] += w * px;
                                    ay[j] += w * py;
                                    axx[j] += w * pxx;
                                    ayy[j] += w * pyy;
                                    axy[j] += w * pxy;
                                }
                            }
                        }
                    }
                }
            } else {
                // x-edge blocks: guarded scalar loads.
#pragma unroll
                for (int i = 0; i < 18; ++i) {
                    const int gx = tx0 + c0 - RAD + i;
                    const bool ok = (gx >= 0) & (gx < IMG);
                    const float px = ok ? prow[gx] : 0.f;
                    const float py = ok ? trow[gx] : 0.f;
                    const float pxx = px * px, pyy = py * py, pxy = px * py;
#pragma unroll
                    for (int j = 0; j < 8; ++j) {
                        const int m = i - j;
                        if (m >= 0 && m < KW) {
                            const float w = W[m];
                            ax[j] += w * px;
                            ay[j] += w * py;
                            axx[j] += w * pxx;
                            ayy[j] += w * pyy;
                            axy[j] += w * pxy;
                        }
                    }
                }
            }
        }
        // Store (zeros when gy out of range == zero padding).
#pragma unroll
        for (int j = 0; j < 8; ++j) {
            shA[r * SA + c0 + j] = __floats2half2_rn(ax[j], ay[j]);
            shB[r * SA + c0 + j] = __floats2half2_rn(axx[j], ayy[j]);
            shC[r * SC + c0 + j] = __float2half_rn(axy[j]);
        }
    }
    __syncthreads();

    // ---- Phase B: vertical filter + combine ----
    {
        const int c = tid & 63;
        const int j0 = (tid >> 6) * 8;   // 8 output rows per thread

        float mx[8] = {0, 0, 0, 0, 0, 0, 0, 0};
        float my[8] = {0, 0, 0, 0, 0, 0, 0, 0};
        float sxx[8] = {0, 0, 0, 0, 0, 0, 0, 0};
        float syy[8] = {0, 0, 0, 0, 0, 0, 0, 0};
        float sxy[8] = {0, 0, 0, 0, 0, 0, 0, 0};

#pragma unroll
        for (int t = 0; t < 18; ++t) {
            const int row = j0 + t;
            const float2 fa = __half22float2(shA[row * SA + c]);
            const float2 fb = __half22float2(shB[row * SA + c]);
            const float fc = __half2float(shC[row * SC + c]);
#pragma unroll
            for (int j = 0; j < 8; ++j) {
                const int m = t - j;
                if (m >= 0 && m < KW) {
                    const float w = W[m];
                    mx[j] += w * fa.x;
                    my[j] += w * fa.y;
                    sxx[j] += w * fb.x;
                    syy[j] += w * fb.y;
                    sxy[j] += w * fc;
                }
            }
        }

#pragma unroll
        for (int j = 0; j < 8; ++j) {
            const int gy = ty0 + j0 + j;
            const int gidx = gy * IMG + tx0 + c;
            const float mu_x = mx[j];
            const float mu_y = my[j];
            const float s2x = sxx[j] - mu_x * mu_x;
            const float s2y = syy[j] - mu_y * mu_y;
            const float cxy = sxy[j] - mu_x * mu_y;

            const float A1 = 2.f * mu_x * mu_y + C1F;
            const float A2 = 2.f * cxy + C2F;
            const float B1 = mu_x * mu_x + mu_y * mu_y + C1F;
            const float B2 = s2x + s2y + C2F;
            const float ssim = (A1 * A2) * __builtin_amdgcn_rcpf(B1 * B2);

            const float rp = pp[gidx];   // L1/L2-hot
            const float rt = tp[gidx];
            const float d = rp - rt;
            const float charb = __builtin_amdgcn_sqrtf(d * d + EPS2);
            op[gidx] = 0.3f * charb + 2.0f * (d * d) + 0.6f * (1.f - ssim);
        }
    }
}

extern "C" void kernel_launch(void* const* d_in, const int* in_sizes, int n_in,
                              void* d_out, int out_size, void* d_ws, size_t ws_size,
                              hipStream_t stream) {
    const float* pred = (const float*)d_in[0];
    const float* target = (const float*)d_in[1];
    float* out = (float*)d_out;
    const int planes = in_sizes[0] / (IMG * IMG);   // 48

    dim3 grid(IMG / TW, IMG / TH, planes);          // 8 x 16 x 48 = 6144
    CombinedLossSSIMCharbMSE_81372450390186_kernel<<<grid, dim3(256), 0, stream>>>(
        pred, target, out);
}

// Round 3
// 346.317 us; speedup vs baseline: 1.5951x; 1.5951x over previous
//
#include <hip/hip_runtime.h>
#include <hip/hip_fp16.h>
#include <math.h>

// Fused separable 11x11 gaussian over {x,y,x2,y2,xy} + SSIM/charb/MSE combine.
// R2: same structure as R1 (fp16 LDS 28.6 KB, float4 interior path) but
// __launch_bounds__(256,4): VGPR cap 128. R1's (256,5) capped VGPRs at 48,
// forcing ~1.6 GB of scratch spill traffic (WRITE_SIZE 961 MB) — this kernel
// needs ~90 VGPRs for its 40 phase-A accumulators; never cap below that.
// Occupancy target: 4 blocks/CU (16 waves) — 2x R0's LDS-limited 2 blocks.

#define TW 64
#define TH 32
#define RAD 5
#define KW 11
#define RAW_H (TH + 2 * RAD)   // 42
#define SA 68                  // half2-array stride (dword entries)
#define SC 68                  // half-array stride
#define IMG 512

#define C1F 1e-4f
#define C2F 9e-4f
#define EPS2 1e-12f

__global__ __launch_bounds__(256, 4)
void CombinedLossSSIMCharbMSE_81372450390186_kernel(
    const float* __restrict__ pred,
    const float* __restrict__ target,
    float* __restrict__ out)
{
    __shared__ __half2 shA[RAW_H * SA];  // (hx, hy)
    __shared__ __half2 shB[RAW_H * SA];  // (hxx, hyy)
    __shared__ __half  shC[RAW_H * SC];  // hxy

    const int tid = threadIdx.x;
    const int bx = blockIdx.x, by = blockIdx.y;
    const int tx0 = bx * TW, ty0 = by * TH;
    const size_t plane = (size_t)blockIdx.z * (IMG * IMG);
    const float* __restrict__ pp = pred + plane;
    const float* __restrict__ tp = target + plane;
    float* __restrict__ op = out + plane;

    // Gaussian weights (sigma=1.5), normalized; registers (compile-time idx).
    float W[KW];
    {
        float s = 0.f;
#pragma unroll
        for (int i = 0; i < KW; ++i) {
            float x = (float)(i - RAD);
            W[i] = __expf(-x * x * (1.0f / (2.0f * 1.5f * 1.5f)));
            s += W[i];
        }
        float inv = 1.0f / s;
#pragma unroll
        for (int i = 0; i < KW; ++i) W[i] *= inv;
    }

    const bool xint = (bx > 0) & (bx < (IMG / TW - 1));

    // ---- Phase A: horizontal filter (fused with global read) ----
    // item = r*8 + cg; r in [0,42), cg = 8-column group.
    for (int item = tid; item < RAW_H * 8; item += 256) {
        const int r = item >> 3;
        const int c0 = (item & 7) * 8;
        const int gy = ty0 - RAD + r;

        float ax[8] = {0, 0, 0, 0, 0, 0, 0, 0};
        float ay[8] = {0, 0, 0, 0, 0, 0, 0, 0};
        float axx[8] = {0, 0, 0, 0, 0, 0, 0, 0};
        float ayy[8] = {0, 0, 0, 0, 0, 0, 0, 0};
        float axy[8] = {0, 0, 0, 0, 0, 0, 0, 0};

        if (gy >= 0 && gy < IMG) {
            const float* __restrict__ prow = pp + gy * IMG;
            const float* __restrict__ trow = tp + gy * IMG;
            if (xint) {
                // Window [tx0+c0-8, tx0+c0+16): 6 aligned float4 loads.
                // Output col c0+j tap k -> rel idx = j + k + 3 in [3,20].
                const int gx0 = tx0 + c0 - 8;
                const float4* __restrict__ p4 = (const float4*)(prow + gx0);
                const float4* __restrict__ t4 = (const float4*)(trow + gx0);
#pragma unroll
                for (int ch = 0; ch < 6; ++ch) {
                    const float4 xv = p4[ch];
                    const float4 yv = t4[ch];
                    const float xs[4] = {xv.x, xv.y, xv.z, xv.w};
                    const float ys[4] = {yv.x, yv.y, yv.z, yv.w};
#pragma unroll
                    for (int q = 0; q < 4; ++q) {
                        const int idx = ch * 4 + q;
                        if (idx >= 3 && idx <= 20) {
                            const float px = xs[q], py = ys[q];
                            const float pxx = px * px, pyy = py * py, pxy = px * py;
#pragma unroll
                            for (int j = 0; j < 8; ++j) {
                                const int m = idx - 3 - j;   // tap index
                                if (m >= 0 && m < KW) {
                                    const float w = W[m];
                                    ax[j] += w * px;
                                    ay[j] += w * py;
                                    axx[j] += w * pxx;
                                    ayy[j] += w * pyy;
                                    axy[j] += w * pxy;
                                }
                            }
                        }
                    }
                }
            } else {
                // x-edge blocks: guarded scalar loads.
#pragma unroll
                for (int i = 0; i < 18; ++i) {
                    const int gx = tx0 + c0 - RAD + i;
                    const bool ok = (gx >= 0) & (gx < IMG);
                    const float px = ok ? prow[gx] : 0.f;
                    const float py = ok ? trow[gx] : 0.f;
                    const float pxx = px * px, pyy = py * py, pxy = px * py;
#pragma unroll
                    for (int j = 0; j < 8; ++j) {
                        const int m = i - j;
                        if (m >= 0 && m < KW) {
                            const float w = W[m];
                            ax[j] += w * px;
                            ay[j] += w * py;
                            axx[j] += w * pxx;
                            ayy[j] += w * pyy;
                            axy[j] += w * pxy;
                        }
                    }
                }
            }
        }
        // Store (zeros when gy out of range == zero padding).
#pragma unroll
        for (int j = 0; j < 8; ++j) {
            shA[r * SA + c0 + j] = __floats2half2_rn(ax[j], ay[j]);
            shB[r * SA + c0 + j] = __floats2half2_rn(axx[j], ayy[j]);
            shC[r * SC + c0 + j] = __float2half_rn(axy[j]);
        }
    }
    __syncthreads();

    // ---- Phase B: vertical filter + combine ----
    {
        const int c = tid & 63;
        const int j0 = (tid >> 6) * 8;   // 8 output rows per thread

        float mx[8] = {0, 0, 0, 0, 0, 0, 0, 0};
        float my[8] = {0, 0, 0, 0, 0, 0, 0, 0};
        float sxx[8] = {0, 0, 0, 0, 0, 0, 0, 0};
        float syy[8] = {0, 0, 0, 0, 0, 0, 0, 0};
        float sxy[8] = {0, 0, 0, 0, 0, 0, 0, 0};

#pragma unroll
        for (int t = 0; t < 18; ++t) {
            const int row = j0 + t;
            const float2 fa = __half22float2(shA[row * SA + c]);
            const float2 fb = __half22float2(shB[row * SA + c]);
            const float fc = __half2float(shC[row * SC + c]);
#pragma unroll
            for (int j = 0; j < 8; ++j) {
                const int m = t - j;
                if (m >= 0 && m < KW) {
                    const float w = W[m];
                    mx[j] += w * fa.x;
                    my[j] += w * fa.y;
                    sxx[j] += w * fb.x;
                    syy[j] += w * fb.y;
                    sxy[j] += w * fc;
                }
            }
        }

#pragma unroll
        for (int j = 0; j < 8; ++j) {
            const int gy = ty0 + j0 + j;
            const int gidx = gy * IMG + tx0 + c;
            const float mu_x = mx[j];
            const float mu_y = my[j];
            const float s2x = sxx[j] - mu_x * mu_x;
            const float s2y = syy[j] - mu_y * mu_y;
            const float cxy = sxy[j] - mu_x * mu_y;

            const float A1 = 2.f * mu_x * mu_y + C1F;
            const float A2 = 2.f * cxy + C2F;
            const float B1 = mu_x * mu_x + mu_y * mu_y + C1F;
            const float B2 = s2x + s2y + C2F;
            const float ssim = (A1 * A2) * __builtin_amdgcn_rcpf(B1 * B2);

            const float rp = pp[gidx];   // L1/L2-hot
            const float rt = tp[gidx];
            const float d = rp - rt;
            const float charb = __builtin_amdgcn_sqrtf(d * d + EPS2);
            op[gidx] = 0.3f * charb + 2.0f * (d * d) + 0.6f * (1.f - ssim);
        }
    }
}

extern "C" void kernel_launch(void* const* d_in, const int* in_sizes, int n_in,
                              void* d_out, int out_size, void* d_ws, size_t ws_size,
                              hipStream_t stream) {
    const float* pred = (const float*)d_in[0];
    const float* target = (const float*)d_in[1];
    float* out = (float*)d_out;
    const int planes = in_sizes[0] / (IMG * IMG);   // 48

    dim3 grid(IMG / TW, IMG / TH, planes);          // 8 x 16 x 48 = 6144
    CombinedLossSSIMCharbMSE_81372450390186_kernel<<<grid, dim3(256), 0, stream>>>(
        pred, target, out);
}

// Round 4
// 248.312 us; speedup vs baseline: 2.2246x; 1.3947x over previous
//
#include <hip/hip_runtime.h>
#include <hip/hip_fp16.h>
#include <math.h>

// Fused separable 11x11 gaussian over {x,y,x2,y2,xy} + SSIM/charb/MSE combine.
// R3: fp16 LDS (28.6 KB) + __launch_bounds__(256,2).
//
// Launch-bounds history (gfx950 treats min-waves as an occupancy TARGET and
// spills to hit it):
//   (256,2): 88 VGPR, no spill, 184 us   <- only spill-free regime
//   (256,4): 64 VGPR, ~700 MB spill traffic, 253 us
//   (256,5): 48 VGPR, ~1.6 GB spill traffic, 464 us
// This kernel's live set is ~90 VGPRs (40 phase-A accumulators). At 88 VGPR
// the HW gives 4 waves/SIMD = 4 blocks/CU; fp16 LDS (28.6 KB) allows 5.
// Net: 2x R0's residency (R0: 54.8 KB LDS -> 2 blocks/CU) with zero spills.

#define TW 64
#define TH 32
#define RAD 5
#define KW 11
#define RAW_H (TH + 2 * RAD)   // 42
#define SA 68                  // half2-array stride (dword entries)
#define SC 68                  // half-array stride
#define IMG 512

#define C1F 1e-4f
#define C2F 9e-4f
#define EPS2 1e-12f

__global__ __launch_bounds__(256, 2)
void CombinedLossSSIMCharbMSE_81372450390186_kernel(
    const float* __restrict__ pred,
    const float* __restrict__ target,
    float* __restrict__ out)
{
    __shared__ __half2 shA[RAW_H * SA];  // (hx, hy)
    __shared__ __half2 shB[RAW_H * SA];  // (hxx, hyy)
    __shared__ __half  shC[RAW_H * SC];  // hxy

    const int tid = threadIdx.x;
    const int bx = blockIdx.x, by = blockIdx.y;
    const int tx0 = bx * TW, ty0 = by * TH;
    const size_t plane = (size_t)blockIdx.z * (IMG * IMG);
    const float* __restrict__ pp = pred + plane;
    const float* __restrict__ tp = target + plane;
    float* __restrict__ op = out + plane;

    // Gaussian weights (sigma=1.5), normalized; registers (compile-time idx).
    float W[KW];
    {
        float s = 0.f;
#pragma unroll
        for (int i = 0; i < KW; ++i) {
            float x = (float)(i - RAD);
            W[i] = __expf(-x * x * (1.0f / (2.0f * 1.5f * 1.5f)));
            s += W[i];
        }
        float inv = 1.0f / s;
#pragma unroll
        for (int i = 0; i < KW; ++i) W[i] *= inv;
    }

    const bool xint = (bx > 0) & (bx < (IMG / TW - 1));

    // ---- Phase A: horizontal filter (fused with global read) ----
    // item = r*8 + cg; r in [0,42), cg = 8-column group.
    for (int item = tid; item < RAW_H * 8; item += 256) {
        const int r = item >> 3;
        const int c0 = (item & 7) * 8;
        const int gy = ty0 - RAD + r;

        float ax[8] = {0, 0, 0, 0, 0, 0, 0, 0};
        float ay[8] = {0, 0, 0, 0, 0, 0, 0, 0};
        float axx[8] = {0, 0, 0, 0, 0, 0, 0, 0};
        float ayy[8] = {0, 0, 0, 0, 0, 0, 0, 0};
        float axy[8] = {0, 0, 0, 0, 0, 0, 0, 0};

        if (gy >= 0 && gy < IMG) {
            const float* __restrict__ prow = pp + gy * IMG;
            const float* __restrict__ trow = tp + gy * IMG;
            if (xint) {
                // Window [tx0+c0-8, tx0+c0+16): 6 aligned float4 loads.
                // Output col c0+j tap k -> rel idx = j + k + 3 in [3,20].
                const int gx0 = tx0 + c0 - 8;
                const float4* __restrict__ p4 = (const float4*)(prow + gx0);
                const float4* __restrict__ t4 = (const float4*)(trow + gx0);
#pragma unroll
                for (int ch = 0; ch < 6; ++ch) {
                    const float4 xv = p4[ch];
                    const float4 yv = t4[ch];
                    const float xs[4] = {xv.x, xv.y, xv.z, xv.w};
                    const float ys[4] = {yv.x, yv.y, yv.z, yv.w};
#pragma unroll
                    for (int q = 0; q < 4; ++q) {
                        const int idx = ch * 4 + q;
                        if (idx >= 3 && idx <= 20) {
                            const float px = xs[q], py = ys[q];
                            const float pxx = px * px, pyy = py * py, pxy = px * py;
#pragma unroll
                            for (int j = 0; j < 8; ++j) {
                                const int m = idx - 3 - j;   // tap index
                                if (m >= 0 && m < KW) {
                                    const float w = W[m];
                                    ax[j] += w * px;
                                    ay[j] += w * py;
                                    axx[j] += w * pxx;
                                    ayy[j] += w * pyy;
                                    axy[j] += w * pxy;
                                }
                            }
                        }
                    }
                }
            } else {
                // x-edge blocks: guarded scalar loads.
#pragma unroll
                for (int i = 0; i < 18; ++i) {
                    const int gx = tx0 + c0 - RAD + i;
                    const bool ok = (gx >= 0) & (gx < IMG);
                    const float px = ok ? prow[gx] : 0.f;
                    const float py = ok ? trow[gx] : 0.f;
                    const float pxx = px * px, pyy = py * py, pxy = px * py;
#pragma unroll
                    for (int j = 0; j < 8; ++j) {
                        const int m = i - j;
                        if (m >= 0 && m < KW) {
                            const float w = W[m];
                            ax[j] += w * px;
                            ay[j] += w * py;
                            axx[j] += w * pxx;
                            ayy[j] += w * pyy;
                            axy[j] += w * pxy;
                        }
                    }
                }
            }
        }
        // Store (zeros when gy out of range == zero padding).
#pragma unroll
        for (int j = 0; j < 8; ++j) {
            shA[r * SA + c0 + j] = __floats2half2_rn(ax[j], ay[j]);
            shB[r * SA + c0 + j] = __floats2half2_rn(axx[j], ayy[j]);
            shC[r * SC + c0 + j] = __float2half_rn(axy[j]);
        }
    }
    __syncthreads();

    // ---- Phase B: vertical filter + combine ----
    {
        const int c = tid & 63;
        const int j0 = (tid >> 6) * 8;   // 8 output rows per thread

        float mx[8] = {0, 0, 0, 0, 0, 0, 0, 0};
        float my[8] = {0, 0, 0, 0, 0, 0, 0, 0};
        float sxx[8] = {0, 0, 0, 0, 0, 0, 0, 0};
        float syy[8] = {0, 0, 0, 0, 0, 0, 0, 0};
        float sxy[8] = {0, 0, 0, 0, 0, 0, 0, 0};

#pragma unroll
        for (int t = 0; t < 18; ++t) {
            const int row = j0 + t;
            const float2 fa = __half22float2(shA[row * SA + c]);
            const float2 fb = __half22float2(shB[row * SA + c]);
            const float fc = __half2float(shC[row * SC + c]);
#pragma unroll
            for (int j = 0; j < 8; ++j) {
                const int m = t - j;
                if (m >= 0 && m < KW) {
                    const float w = W[m];
                    mx[j] += w * fa.x;
                    my[j] += w * fa.y;
                    sxx[j] += w * fb.x;
                    syy[j] += w * fb.y;
                    sxy[j] += w * fc;
                }
            }
        }

#pragma unroll
        for (int j = 0; j < 8; ++j) {
            const int gy = ty0 + j0 + j;
            const int gidx = gy * IMG + tx0 + c;
            const float mu_x = mx[j];
            const float mu_y = my[j];
            const float s2x = sxx[j] - mu_x * mu_x;
            const float s2y = syy[j] - mu_y * mu_y;
            const float cxy = sxy[j] - mu_x * mu_y;

            const float A1 = 2.f * mu_x * mu_y + C1F;
            const float A2 = 2.f * cxy + C2F;
            const float B1 = mu_x * mu_x + mu_y * mu_y + C1F;
            const float B2 = s2x + s2y + C2F;
            const float ssim = (A1 * A2) * __builtin_amdgcn_rcpf(B1 * B2);

            const float rp = pp[gidx];   // L1/L2-hot
            const float rt = tp[gidx];
            const float d = rp - rt;
            const float charb = __builtin_amdgcn_sqrtf(d * d + EPS2);
            op[gidx] = 0.3f * charb + 2.0f * (d * d) + 0.6f * (1.f - ssim);
        }
    }
}

extern "C" void kernel_launch(void* const* d_in, const int* in_sizes, int n_in,
                              void* d_out, int out_size, void* d_ws, size_t ws_size,
                              hipStream_t stream) {
    const float* pred = (const float*)d_in[0];
    const float* target = (const float*)d_in[1];
    float* out = (float*)d_out;
    const int planes = in_sizes[0] / (IMG * IMG);   // 48

    dim3 grid(IMG / TW, IMG / TH, planes);          // 8 x 16 x 48 = 6144
    CombinedLossSSIMCharbMSE_81372450390186_kernel<<<grid, dim3(256), 0, stream>>>(
        pred, target, out);
}

// Round 5
// 237.957 us; speedup vs baseline: 2.3214x; 1.0435x over previous
//
#include <hip/hip_runtime.h>
#include <hip/hip_fp16.h>

// Fused separable 11x11 gaussian + SSIM/charb/MSE combine.
// R4: 4 filtered quantities instead of 5 — SSIM identity:
//   B2 = G(x^2+y^2) - mu_x^2 - mu_y^2 + C2,  sigma_xy = G(xy) - mu_x*mu_y
// so we filter {x, y, x^2+y^2, x*y} only. Effects:
//   - FMAs -20% in both passes
//   - LDS 28.6 -> 21.7 KB (7 blocks/CU by LDS)
//   - phase-A accumulators 40 -> 32 regs; weights hard-coded as literals
//     (live in SGPRs, not VGPRs, saving ~11 VGPRs)
//   - live set ~50 VGPR -> (256,4)'s 64-VGPR cap fits WITHOUT spilling.
// Spill history: R2's (256,4) spilled because live set was ~90. Tripwire:
// WRITE_SIZE must stay ~49 MB; if it grows, the cap is still too tight.
// VGPR<=64 puts us in the 8-waves/SIMD bin (m69: waves halve at 64/128/256).

#define TW 64
#define TH 32
#define RAD 5
#define KW 11
#define RAW_H (TH + 2 * RAD)   // 42
#define SAB 66                 // HPack stride per row (8 B units)
#define IMG 512

#define C1F 1e-4f
#define C2F 9e-4f
#define EPS2 1e-12f

// Gaussian(sigma=1.5, K=11), normalized; literals -> SGPRs at codegen.
#define W0 0.00102838f
#define W1 0.00759876f
#define W2 0.03600076f
#define W3 0.10936067f
#define W4 0.21300537f
#define W5 0.26601297f
__device__ __constant__ const float GW[KW] = {W0, W1, W2, W3, W4, W5, W4, W3, W2, W1, W0};

struct __align__(8) HPack {
    __half2 xy;   // (G_h(x), G_h(y))
    __half2 sp;   // (G_h(x^2+y^2), G_h(x*y))
};

__global__ __launch_bounds__(256, 4)
void CombinedLossSSIMCharbMSE_81372450390186_kernel(
    const float* __restrict__ pred,
    const float* __restrict__ target,
    float* __restrict__ out)
{
    __shared__ HPack sh[RAW_H * SAB];   // 42*66*8 = 22176 B

    const int tid = threadIdx.x;
    const int bx = blockIdx.x, by = blockIdx.y;
    const int tx0 = bx * TW, ty0 = by * TH;
    const size_t plane = (size_t)blockIdx.z * (IMG * IMG);
    const float* __restrict__ pp = pred + plane;
    const float* __restrict__ tp = target + plane;
    float* __restrict__ op = out + plane;

    const bool xint = (bx > 0) & (bx < (IMG / TW - 1));

    // ---- Phase A: horizontal filter fused with global read ----
    // item = r*8 + cg; r in [0,42), cg = 8-col group. 336 items, 2 sweeps.
    for (int item = tid; item < RAW_H * 8; item += 256) {
        const int r = item >> 3;
        const int c0 = (item & 7) * 8;
        const int gy = ty0 - RAD + r;

        float ax[8] = {0, 0, 0, 0, 0, 0, 0, 0};
        float ay[8] = {0, 0, 0, 0, 0, 0, 0, 0};
        float as[8] = {0, 0, 0, 0, 0, 0, 0, 0};
        float ap[8] = {0, 0, 0, 0, 0, 0, 0, 0};

        if (gy >= 0 && gy < IMG) {
            const float* __restrict__ prow = pp + gy * IMG;
            const float* __restrict__ trow = tp + gy * IMG;
            if (xint) {
                // Window [tx0+c0-8, tx0+c0+16): 6 aligned float4 loads each.
                // Output col c0+j, tap m -> rel idx = j + m + 3 in [3,20].
                const int gx0 = tx0 + c0 - 8;
                const float4* __restrict__ p4 = (const float4*)(prow + gx0);
                const float4* __restrict__ t4 = (const float4*)(trow + gx0);
#pragma unroll
                for (int ch = 0; ch < 6; ++ch) {
                    const float4 xv = p4[ch];
                    const float4 yv = t4[ch];
                    const float xs[4] = {xv.x, xv.y, xv.z, xv.w};
                    const float ys[4] = {yv.x, yv.y, yv.z, yv.w};
#pragma unroll
                    for (int q = 0; q < 4; ++q) {
                        const int idx = ch * 4 + q;
                        if (idx >= 3 && idx <= 20) {
                            const float px = xs[q], py = ys[q];
                            const float ss = px * px + py * py;
                            const float pr = px * py;
#pragma unroll
                            for (int j = 0; j < 8; ++j) {
                                const int m = idx - 3 - j;
                                if (m >= 0 && m < KW) {
                                    const float w = GW[m];
                                    ax[j] += w * px;
                                    ay[j] += w * py;
                                    as[j] += w * ss;
                                    ap[j] += w * pr;
                                }
                            }
                        }
                    }
                }
            } else {
                // x-edge blocks: guarded scalar loads.
#pragma unroll
                for (int i = 0; i < 18; ++i) {
                    const int gx = tx0 + c0 - RAD + i;
                    const bool ok = (gx >= 0) & (gx < IMG);
                    const float px = ok ? prow[gx] : 0.f;
                    const float py = ok ? trow[gx] : 0.f;
                    const float ss = px * px + py * py;
                    const float pr = px * py;
#pragma unroll
                    for (int j = 0; j < 8; ++j) {
                        const int m = i - j;
                        if (m >= 0 && m < KW) {
                            const float w = GW[m];
                            ax[j] += w * px;
                            ay[j] += w * py;
                            as[j] += w * ss;
                            ap[j] += w * pr;
                        }
                    }
                }
            }
        }
        // Zeros when gy out of range == zero padding.
#pragma unroll
        for (int j = 0; j < 8; ++j) {
            HPack h;
            h.xy = __floats2half2_rn(ax[j], ay[j]);
            h.sp = __floats2half2_rn(as[j], ap[j]);
            sh[r * SAB + c0 + j] = h;
        }
    }
    __syncthreads();

    // ---- Phase B: vertical filter + combine ----
    {
        const int c = tid & 63;
        const int j0 = (tid >> 6) * 8;   // 8 output rows per thread

        float mx[8] = {0, 0, 0, 0, 0, 0, 0, 0};
        float my[8] = {0, 0, 0, 0, 0, 0, 0, 0};
        float ms[8] = {0, 0, 0, 0, 0, 0, 0, 0};
        float mp[8] = {0, 0, 0, 0, 0, 0, 0, 0};

#pragma unroll
        for (int t = 0; t < 18; ++t) {
            const HPack v = sh[(j0 + t) * SAB + c];   // one ds_read_b64
            const float2 fxy = __half22float2(v.xy);
            const float2 fsp = __half22float2(v.sp);
#pragma unroll
            for (int j = 0; j < 8; ++j) {
                const int m = t - j;
                if (m >= 0 && m < KW) {
                    const float w = GW[m];
                    mx[j] += w * fxy.x;
                    my[j] += w * fxy.y;
                    ms[j] += w * fsp.x;
                    mp[j] += w * fsp.y;
                }
            }
        }

#pragma unroll
        for (int j = 0; j < 8; ++j) {
            const int gy = ty0 + j0 + j;
            const int gidx = gy * IMG + tx0 + c;
            const float mu_x = mx[j];
            const float mu_y = my[j];
            const float mu2 = mu_x * mu_x + mu_y * mu_y;

            const float A1 = 2.f * mu_x * mu_y + C1F;
            const float A2 = 2.f * (mp[j] - mu_x * mu_y) + C2F;
            const float B1 = mu2 + C1F;
            const float B2 = (ms[j] - mu2) + C2F;
            const float ssim = (A1 * A2) * __builtin_amdgcn_rcpf(B1 * B2);

            const float rp = pp[gidx];   // L1/L2-hot (loaded in phase A)
            const float rt = tp[gidx];
            const float d = rp - rt;
            const float charb = __builtin_amdgcn_sqrtf(d * d + EPS2);
            op[gidx] = 0.3f * charb + 2.0f * (d * d) + 0.6f * (1.f - ssim);
        }
    }
}

extern "C" void kernel_launch(void* const* d_in, const int* in_sizes, int n_in,
                              void* d_out, int out_size, void* d_ws, size_t ws_size,
                              hipStream_t stream) {
    const float* pred = (const float*)d_in[0];
    const float* target = (const float*)d_in[1];
    float* out = (float*)d_out;
    const int planes = in_sizes[0] / (IMG * IMG);   // 48

    dim3 grid(IMG / TW, IMG / TH, planes);          // 8 x 16 x 48 = 6144
    CombinedLossSSIMCharbMSE_81372450390186_kernel<<<grid, dim3(256), 0, stream>>>(
        pred, target, out);
}

// Round 6
// 189.783 us; speedup vs baseline: 2.9107x; 1.2538x over previous
//
#include <hip/hip_runtime.h>

// Fused separable 11x11 gaussian + SSIM/charb/MSE, wave-streaming form.
// R5: NO __syncthreads. Each wave owns a 64-col x 32-row tile and streams
// 42 input rows. Per row: coalesced 74-wide halo load -> wave-private
// double-buffered LDS row (1.2 KB/wave) -> 11 ds_read_b64 taps ->
// horizontal filter of {x, y, x^2+y^2, x*y} -> vertical accumulation into
// an 11-deep register ring (44 fp32 accs, compile-time indices via mod-11
// unroll) -> one output row finalized per step. Charb diff kept in an
// 11-deep register ring. Pure fp32 (no half converts).
// Why: R0-R4 all measured ~8 resident waves/CU with VALUBusy<=45% — the
// block-phase + barrier structure was the latency sink (plus phase-A's
// 336-items-on-256-threads wave imbalance). This form has balanced lanes,
// zero barriers, and 44 independent FMA chains per wave.
// Ring algebra: at step i (u=i%11), slot s holds output row delta
// d=i-((i-s) mod 11); tap weight GW[(u-s) mod 11]; slot f=(u+1)%11
// finalizes at step i (o = row0+i-10) then is zeroed for row o+11.

#define IMG    512
#define RAD    5
#define KW     11
#define STRH   32
#define NSTEP  (STRH + 2 * RAD)   // 42
#define ROWE   74                 // halo row entries (64 + 2*5)
#define PLANE  (IMG * IMG)

#define C1F  1e-4f
#define C2F  9e-4f
#define EPS2 1e-12f

#define W0 0.00102838f
#define W1 0.00759876f
#define W2 0.03600076f
#define W3 0.10936067f
#define W4 0.21300537f
#define W5 0.26601297f

__global__ __launch_bounds__(256, 2)
void CombinedLossSSIMCharbMSE_81372450390186_kernel(
    const float* __restrict__ pred,
    const float* __restrict__ target,
    float* __restrict__ out)
{
    const float GW[KW] = {W0, W1, W2, W3, W4, W5, W4, W3, W2, W1, W0};

    __shared__ float2 rb[8 * ROWE];   // 4 waves x 2 row buffers, 4736 B

    const int lane = threadIdx.x & 63;
    const int wav  = threadIdx.x >> 6;
    const int wid  = (blockIdx.x << 2) | wav;   // global wave id
    const int plane = wid >> 7;                 // 128 waves per plane
    const int tile  = (wid >> 3) & 15;          // 16 row-tiles
    const int strip = wid & 7;                  // 8 col-strips
    const int col0 = strip << 6;
    const int row0 = tile << 5;
    const int pbase = plane * PLANE;

    // Column geometry (constant across rows). Entry e <-> col col0-5+e.
    const int  cA  = col0 - RAD + lane;         // entries 0..63
    const bool okA = (cA >= 0) & (cA < IMG);
    const int  cAc = min(max(cA, 0), IMG - 1);
    const int  cB  = col0 + 59 + lane;          // entries 64..73 (lanes 0..9)
    const bool okB = cB < IMG;
    const int  cBc = min(cB, IMG - 1);
    const bool doB = lane < 10;

    float accx[KW], accy[KW], accs[KW], accp[KW], dring[KW];
#pragma unroll
    for (int s = 0; s < KW; ++s) {
        accx[s] = 0.f; accy[s] = 0.f; accs[s] = 0.f; accp[s] = 0.f; dring[s] = 0.f;
    }

    for (int k = 0; k < 4; ++k) {
#pragma unroll
        for (int u = 0; u < KW; ++u) {
            const int i = k * KW + u;           // step index 0..43 (42,43 cut)
            if (i >= NSTEP) break;              // wave-uniform
            const int r = row0 - RAD + i;       // input row

            if (r >= 0 && r < IMG) {            // wave-uniform (zero-pad rows)
                const int base = pbase + r * IMG;
                float pA = pred[base + cAc];   pA = okA ? pA : 0.f;
                float tA = target[base + cAc]; tA = okA ? tA : 0.f;
                float pB = 0.f, tB = 0.f;
                if (doB) {
                    pB = pred[base + cBc];   pB = okB ? pB : 0.f;
                    tB = target[base + cBc]; tB = okB ? tB : 0.f;
                }
                float2* wrb = &rb[(wav * 2 + (i & 1)) * ROWE];  // dbuf parity
                wrb[lane] = make_float2(pA, tA);
                if (doB) wrb[64 + lane] = make_float2(pB, tB);
                __builtin_amdgcn_wave_barrier();  // keep write->read order

                // Horizontal taps: entry lane+d = col (col0+lane) + d - 5.
                float2 tv[KW];
#pragma unroll
                for (int d = 0; d < KW; ++d) tv[d] = wrb[lane + d];

                float hx = 0.f, hy = 0.f, hs = 0.f, hp = 0.f;
#pragma unroll
                for (int d = 0; d < KW; ++d) {
                    const float px = tv[d].x, py = tv[d].y;
                    const float w = GW[d];
                    hx = fmaf(w, px, hx);
                    hy = fmaf(w, py, hy);
                    hs = fmaf(w, fmaf(px, px, py * py), hs);
                    hp = fmaf(w, px * py, hp);
                }
                dring[u] = tv[RAD].x - tv[RAD].y;   // center diff, used i+5

                // Vertical accumulation into the 11-slot ring.
#pragma unroll
                for (int s = 0; s < KW; ++s) {
                    const float w = GW[(u - s + KW) % KW];
                    accx[s] = fmaf(w, hx, accx[s]);
                    accy[s] = fmaf(w, hy, accy[s]);
                    accs[s] = fmaf(w, hs, accs[s]);
                    accp[s] = fmaf(w, hp, accp[s]);
                }
            }

            const int f = (u + 1) % KW;         // slot completing at step i
            if (i >= 2 * RAD) {                 // wave-uniform
                const int o = row0 + i - 2 * RAD;
                const float mu_x = accx[f], mu_y = accy[f];
                const float mxy = mu_x * mu_y;
                const float mu2 = fmaf(mu_x, mu_x, mu_y * mu_y);
                const float A1 = fmaf(2.f, mxy, C1F);
                const float A2 = fmaf(2.f, accp[f] - mxy, C2F);
                const float B1 = mu2 + C1F;
                const float B2 = (accs[f] - mu2) + C2F;
                const float ssim = (A1 * A2) * __builtin_amdgcn_rcpf(B1 * B2);
                const float d = dring[(u + 6) % KW];   // written at step i-5
                const float charb = __builtin_amdgcn_sqrtf(fmaf(d, d, EPS2));
                const float loss =
                    fmaf(0.3f, charb, fmaf(2.0f, d * d, 0.6f * (1.f - ssim)));
                out[pbase + o * IMG + col0 + lane] = loss;
            }
            accx[f] = 0.f; accy[f] = 0.f; accs[f] = 0.f; accp[f] = 0.f;
        }
    }
}

extern "C" void kernel_launch(void* const* d_in, const int* in_sizes, int n_in,
                              void* d_out, int out_size, void* d_ws, size_t ws_size,
                              hipStream_t stream) {
    const float* pred = (const float*)d_in[0];
    const float* target = (const float*)d_in[1];
    float* out = (float*)d_out;
    const int planes = in_sizes[0] / PLANE;     // 48

    // 128 waves per plane (8 strips x 16 tiles), 4 waves per block.
    dim3 grid(planes * 32);                     // 1536 blocks
    CombinedLossSSIMCharbMSE_81372450390186_kernel<<<grid, dim3(256), 0, stream>>>(
        pred, target, out);
}